// Round 1
// 167.889 us; speedup vs baseline: 1.2550x; 1.2550x over previous
//
#include <hip/hip_runtime.h>
#include <cstdint>
#include <cstddef>

#define HIDDEN 1024
#define BATCH 4
#define SEQ 4096
#define M_ROWS (BATCH * SEQ)   // 16384
#define K_DIM 1024
#define SUBCHUNK 32
#define NSUB (SEQ / SUBCHUNK)  // 128

typedef __bf16 bf16_t;
typedef __bf16 v8bf __attribute__((ext_vector_type(8)));
typedef float v4f __attribute__((ext_vector_type(4)));

__device__ __forceinline__ unsigned short f32_to_bf16(float f) {
  unsigned int u = __float_as_uint(f);
  u += 0x7fffu + ((u >> 16) & 1u);   // round-to-nearest-even
  return (unsigned short)(u >> 16);
}
__device__ __forceinline__ float bf16_to_f32(unsigned short u) {
  return __uint_as_float((unsigned int)u << 16);
}

// ---- Merged convert: X fp32->bf16 (blocks 0..16383) and
//      Wb = (W0+W1)/8 | W1 | W2 as bf16 (blocks 16384..19455) ----
__global__ void convert_kernel(const float* __restrict__ X,
                               const float* __restrict__ W0,
                               const float* __restrict__ W1,
                               const float* __restrict__ W2,
                               unsigned short* __restrict__ Xb,
                               unsigned short* __restrict__ Wb) {
  int bx = blockIdx.x;
  if (bx < 16384) {
    int i = bx * 256 + threadIdx.x;        // over 4,194,304 float4s (exact)
    float4 f = ((const float4*)X)[i];
    ushort4 u;
    u.x = f32_to_bf16(f.x); u.y = f32_to_bf16(f.y);
    u.z = f32_to_bf16(f.z); u.w = f32_to_bf16(f.w);
    ((ushort4*)Xb)[i] = u;
  } else {
    int i = (bx - 16384) * 256 + threadIdx.x;  // over 786,432 float4s (exact)
    int mat = i >> 18;                          // 262,144 float4 per matrix
    int off = i & 0x3FFFF;
    float4 f;
    if (mat == 0) {
      float4 a = ((const float4*)W0)[off];
      float4 b = ((const float4*)W1)[off];
      f.x = (a.x + b.x) * 0.125f; f.y = (a.y + b.y) * 0.125f;
      f.z = (a.z + b.z) * 0.125f; f.w = (a.w + b.w) * 0.125f;
    } else {
      const float* src = (mat == 1) ? W1 : W2;
      f = ((const float4*)src)[off];
    }
    ushort4 u;
    u.x = f32_to_bf16(f.x); u.y = f32_to_bf16(f.y);
    u.z = f32_to_bf16(f.z); u.w = f32_to_bf16(f.w);
    ((ushort4*)Wb)[i] = u;
  }
}

// ---- bf16 GEMM, 256x256 tile, BK=64, 8 waves (2Mx4N), 8-phase schedule
// with counted vmcnt (T3+T4), setprio around MFMA bursts (T5), k-chunk XOR
// LDS swizzle (conflict-free, both-sides: pre-swizzled global source +
// swizzled ds_read), XCD-swizzled block mapping (T1).
// C[m][n] = sum_k A[m][k]*B[n][k];  A:[16384][1024], B:[3072][1024] (B^T).
// mat==0 blocks run fused in-subchunk-cummax epilogue; mat 1/2 store C1/C2.
// LDS: 128 KiB dynamic = 2 dbuf x (A 256x64 + B 256x64) bf16.
__global__ __launch_bounds__(512, 2) void gemm256_kernel(
    const bf16_t* __restrict__ A, const bf16_t* __restrict__ B,
    unsigned short* __restrict__ Lp, unsigned short* __restrict__ C1p,
    unsigned short* __restrict__ C2p, float* __restrict__ cmax) {
  extern __shared__ __align__(16) char smem[];   // 131072 B

  const int tid = threadIdx.x;
  const int wave = tid >> 6;     // 0..7
  const int lane = tid & 63;
  const int quad = lane >> 4;    // 0..3
  const int r16 = lane & 15;
  const int wr = wave >> 2;      // 0..1 -> 128-row half
  const int wc = wave & 3;       // 0..3 -> 64-col quarter

  // Bijective XCD swizzle: 768 blocks = 8 XCDs x 96; XCD k gets m-tiles [8k,8k+8)
  const int orig = (int)blockIdx.x;
  const int swz = (orig & 7) * 96 + (orig >> 3);
  const int bx = swz % 12;       // n-tile (12 = 3 matrices x 4 tiles)
  const int mt = swz / 12;       // m-tile (64)
  const int mtile0 = mt * 256;
  const int nbase = bx * 256;

  // Staging: LDS dest is linear (base + lane*16); swizzle applied on the
  // GLOBAL source address. LDS slot (row m, 16B-chunk c) holds global
  // k-chunk c ^ (m&7).  Lane l covers row (+l>>3), chunk l&7 -> source
  // chunk (l&7)^(l>>3).
  const int l3 = lane >> 3;
  const int lc = lane & 7;
  const size_t laneOff = (size_t)l3 * K_DIM + (size_t)((lc ^ l3) << 3);
  const bf16_t* Ag = A + (size_t)(mtile0 + wave * 8) * K_DIM + laneOff;
  const bf16_t* Bg = B + (size_t)(nbase + wave * 8) * K_DIM + laneOff;

  // ds_read addressing: row m = wr*128 + i*16 + r16 (A) / wc*64 + j*16 + r16 (B),
  // desired chunk kk*4+quad stored at chunk (kk*4+quad)^(r16&7).
  const int aRow = (wr * 128 + r16) * 128;   // bytes (row stride 128B)
  const int bRow = (wc * 64 + r16) * 128;
  const int cxor = (r16 & 7) * 16;
  const int qx = quad * 16;

  v4f acc[8][4];
#pragma unroll
  for (int i = 0; i < 8; ++i)
#pragma unroll
    for (int j = 0; j < 4; ++j) acc[i][j] = (v4f)(0.0f);

  v8bf afr[4];
  v8bf bfr[4][2];

#define STG_A(d, q, kt) __builtin_amdgcn_global_load_lds( \
    (__attribute__((address_space(1))) void*)(Ag + (size_t)(q) * (64 * K_DIM) + (size_t)(kt) * 64), \
    (__attribute__((address_space(3))) void*)(smem + (d) * 32768 + (q) * 8192 + wave * 1024), 16, 0, 0)
#define STG_B(d, q, kt) __builtin_amdgcn_global_load_lds( \
    (__attribute__((address_space(1))) void*)(Bg + (size_t)(q) * (64 * K_DIM) + (size_t)(kt) * 64), \
    (__attribute__((address_space(3))) void*)(smem + 65536 + (d) * 32768 + (q) * 8192 + wave * 1024), 16, 0, 0)
#define LDA(d, i, kk) (*(const v8bf*)(smem + (d) * 32768 + aRow + (i) * 2048 + (((kk) * 64 + qx) ^ cxor)))
#define LDB(d, j, kk) (*(const v8bf*)(smem + 65536 + (d) * 32768 + bRow + (j) * 2048 + (((kk) * 64 + qx) ^ cxor)))
#define RD_A(d, ih, kk) { _Pragma("unroll") for (int ii = 0; ii < 4; ++ii) afr[ii] = LDA(d, (ih) * 4 + ii, kk); }
#define RD_B(d, kk) { _Pragma("unroll") for (int j = 0; j < 4; ++j) bfr[j][kk] = LDB(d, j, kk); }
#define MM(ih, kk) \
  __builtin_amdgcn_s_barrier(); \
  asm volatile("s_waitcnt lgkmcnt(0)" ::: "memory"); \
  __builtin_amdgcn_s_setprio(1); \
  { _Pragma("unroll") for (int ii = 0; ii < 4; ++ii) { _Pragma("unroll") for (int j = 0; j < 4; ++j) \
      acc[(ih) * 4 + ii][j] = __builtin_amdgcn_mfma_f32_16x16x32_bf16(afr[ii], bfr[j][(kk)], acc[(ih) * 4 + ii][j], 0, 0, 0); } } \
  __builtin_amdgcn_s_setprio(0);
#define BAR() __builtin_amdgcn_s_barrier()
#define WAITV(n) asm volatile("s_waitcnt vmcnt(" #n ")" ::: "memory")

  // ---- Prologue: tile0 full -> buf0 (8 oldest), tile1 partial -> buf1 (4) ----
  STG_A(0, 0, 0); STG_A(0, 1, 0); STG_A(0, 2, 0); STG_A(0, 3, 0);
  STG_B(0, 0, 0); STG_B(0, 1, 0); STG_B(0, 2, 0); STG_B(0, 3, 0);
  STG_A(1, 0, 1); STG_A(1, 2, 1); STG_B(1, 0, 1); STG_B(1, 1, 1);
  WAITV(4);                    // drain tile0's 8; leave tile1's 4 in flight
  BAR();

  // ---- Main loop: iter computes tiles 2it (buf0), 2it+1 (buf1);
  //      stages 2it+1 remainder, 2it+2 (buf0), 2it+3 (buf1 start). ----
  for (int it = 0; it < 7; ++it) {
    const int t1 = 2 * it + 1, t2 = t1 + 1, t3 = t1 + 2;
    // ph1: buf0 (ih0,kk0); B1.Q2/Q3 <- t1
    RD_A(0, 0, 0); RD_B(0, 0);
    STG_B(1, 2, t1); STG_B(1, 3, t1);
    MM(0, 0); BAR();
    // ph2: buf0 (ih0,kk1); A1.Q1/Q3 <- t1
    RD_B(0, 1); RD_A(0, 0, 1);
    STG_A(1, 1, t1); STG_A(1, 3, t1);
    MM(0, 1); BAR();
    // ph3: buf0 (ih1,kk0); A0.Q0/Q2 <- t2
    RD_A(0, 1, 0);
    STG_A(0, 0, t2); STG_A(0, 2, t2);
    MM(1, 0); BAR();
    // ph4: buf0 (ih1,kk1); B0.Q0/Q1 <- t2; counted wait for tile t1
    RD_A(0, 1, 1);
    STG_B(0, 0, t2); STG_B(0, 1, t2);
    MM(1, 1); WAITV(4); BAR();
    // ph5: buf1 (ih0,kk0); B0.Q2/Q3 <- t2
    RD_A(1, 0, 0); RD_B(1, 0);
    STG_B(0, 2, t2); STG_B(0, 3, t2);
    MM(0, 0); BAR();
    // ph6: buf1 (ih0,kk1); A0.Q1/Q3 <- t2
    RD_B(1, 1); RD_A(1, 0, 1);
    STG_A(0, 1, t2); STG_A(0, 3, t2);
    MM(0, 1); BAR();
    // ph7: buf1 (ih1,kk0); A1.Q0/Q2 <- t3
    RD_A(1, 1, 0);
    STG_A(1, 0, t3); STG_A(1, 2, t3);
    MM(1, 0); BAR();
    // ph8: buf1 (ih1,kk1); B1.Q0/Q1 <- t3; counted wait for tile t2
    RD_A(1, 1, 1);
    STG_B(1, 0, t3); STG_B(1, 1, t3);
    MM(1, 1); WAITV(4); BAR();
  }
  // ---- Tail (it = 7): tiles 14 (buf0), 15 (buf1); only t1=15 staging ----
  RD_A(0, 0, 0); RD_B(0, 0);
  STG_B(1, 2, 15); STG_B(1, 3, 15);
  MM(0, 0); BAR();
  RD_B(0, 1); RD_A(0, 0, 1);
  STG_A(1, 1, 15); STG_A(1, 3, 15);
  MM(0, 1); BAR();
  RD_A(0, 1, 0); MM(1, 0); BAR();
  RD_A(0, 1, 1); MM(1, 1); WAITV(0); BAR();
  RD_A(1, 0, 0); RD_B(1, 0); MM(0, 0); BAR();
  RD_B(1, 1); RD_A(1, 0, 1); MM(0, 1); BAR();
  RD_A(1, 1, 0); MM(1, 0); BAR();
  RD_A(1, 1, 1); MM(1, 1);

#undef STG_A
#undef STG_B
#undef LDA
#undef LDB
#undef RD_A
#undef RD_B
#undef MM
#undef BAR
#undef WAITV

  // ---- Epilogue. C/D layout: col=lane&15, row=quad*4+reg (m89/m91). ----
  const int mat = bx >> 2;
  const int ncol0 = (bx & 3) * 256;

  if (mat != 0) {
    unsigned short* Cm = (mat == 1) ? C1p : C2p;
#pragma unroll
    for (int i = 0; i < 8; ++i)
#pragma unroll
      for (int j = 0; j < 4; ++j)
#pragma unroll
        for (int r = 0; r < 4; ++r) {
          int row = mtile0 + wr * 128 + i * 16 + quad * 4 + r;
          int col = ncol0 + wc * 64 + j * 16 + r16;
          Cm[(size_t)row * HIDDEN + col] = f32_to_bf16(acc[i][j][r]);
        }
    return;
  }

  // mat==0: in-register inclusive cummax over each 32-row subchunk.
  // Wave owns 128 rows = 4 subchunks; subchunk s covers acc i=2s,2s+1.
  const int bidx = mtile0 >> 12;
  const int sub0 = (mtile0 & 4095) >> 5;
#pragma unroll
  for (int s = 0; s < 4; ++s) {
#pragma unroll
    for (int j = 0; j < 4; ++j) {
      float c0[4], c1[4];
      c0[0] = acc[s * 2][j][0];
      c1[0] = acc[s * 2 + 1][j][0];
#pragma unroll
      for (int r = 1; r < 4; ++r) {
        c0[r] = fmaxf(c0[r - 1], acc[s * 2][j][r]);
        c1[r] = fmaxf(c1[r - 1], acc[s * 2 + 1][j][r]);
      }
      float t0 = c0[3], t1 = c1[3], u;
      // inclusive Hillis-Steele over quads (lane stride 16, same column)
      u = __shfl_up(t0, 16); if (quad >= 1) t0 = fmaxf(t0, u);
      u = __shfl_up(t0, 32); if (quad >= 2) t0 = fmaxf(t0, u);
      u = __shfl_up(t1, 16); if (quad >= 1) t1 = fmaxf(t1, u);
      u = __shfl_up(t1, 32); if (quad >= 2) t1 = fmaxf(t1, u);
      float e0 = __shfl_up(t0, 16); if (quad == 0) e0 = -INFINITY;
      float e1 = __shfl_up(t1, 16); if (quad == 0) e1 = -INFINITY;
      float T0 = __shfl(t0, 48 + r16);   // full total of first 16-row half
      float T1 = __shfl(t1, 48 + r16);
      int col = ncol0 + wc * 64 + j * 16 + r16;
      int rowb = mtile0 + wr * 128 + s * 32 + quad * 4;
#pragma unroll
      for (int r = 0; r < 4; ++r) {
        float L0 = fmaxf(c0[r], e0);
        float L1 = fmaxf(fmaxf(c1[r], e1), T0);
        Lp[(size_t)(rowb + r) * HIDDEN + col] = f32_to_bf16(L0);
        Lp[(size_t)(rowb + 16 + r) * HIDDEN + col] = f32_to_bf16(L1);
      }
      if (quad == 0) {
        int sub = sub0 + wr * 4 + s;
        cmax[((size_t)bidx * NSUB + sub) * HIDDEN + col] = fmaxf(T0, T1);
      }
    }
  }
}

// ---- Exclusive prefix-max over subchunks (L2-resident, 2 MB) ----
__global__ void prefix_kernel(const float* __restrict__ cmax,
                              float* __restrict__ pmax) {
  int col = blockIdx.x * 256 + threadIdx.x;
  int b = blockIdx.y;
  const float* cp = cmax + (size_t)b * NSUB * HIDDEN + col;
  float* pp = pmax + (size_t)b * NSUB * HIDDEN + col;
  float run = -INFINITY;
#pragma unroll 4
  for (int s = 0; s < NSUB; ++s) {
    pp[(size_t)s * HIDDEN] = run;
    run = fmaxf(run, cp[(size_t)s * HIDDEN]);
  }
}

// ---- Final: pure elementwise, one row per block ----
__global__ void final_kernel(const unsigned short* __restrict__ L,
                             const unsigned short* __restrict__ C1,
                             const unsigned short* __restrict__ C2,
                             const float* __restrict__ pmax,
                             float* __restrict__ out) {
  const int col = threadIdx.x * 4;
  const int s = blockIdx.x;
  const int b = blockIdx.y;
  const int sub = s >> 5;
  float4 p = *(const float4*)(pmax + ((size_t)b * NSUB + sub) * HIDDEN + col);
  size_t base = ((size_t)b * SEQ + s) * HIDDEN + col;
  ushort4 ul = *(const ushort4*)(L + base);
  ushort4 u1 = *(const ushort4*)(C1 + base);
  ushort4 u2 = *(const ushort4*)(C2 + base);
  float m0 = fmaxf(p.x, bf16_to_f32(ul.x));
  float m1 = fmaxf(p.y, bf16_to_f32(ul.y));
  float m2 = fmaxf(p.z, bf16_to_f32(ul.z));
  float m3 = fmaxf(p.w, bf16_to_f32(ul.w));
  float4 o;
  o.x = (m0 + bf16_to_f32(u2.x)) * m0 + bf16_to_f32(u1.x);
  o.y = (m1 + bf16_to_f32(u2.y)) * m1 + bf16_to_f32(u1.y);
  o.z = (m2 + bf16_to_f32(u2.z)) * m2 + bf16_to_f32(u1.z);
  o.w = (m3 + bf16_to_f32(u2.w)) * m3 + bf16_to_f32(u1.w);
  *(float4*)(out + base) = o;
}

extern "C" void kernel_launch(void* const* d_in, const int* in_sizes, int n_in,
                              void* d_out, int out_size, void* d_ws, size_t ws_size,
                              hipStream_t stream) {
  const float* X = (const float*)d_in[0];
  const float* W0 = (const float*)d_in[1];
  const float* W1 = (const float*)d_in[2];
  const float* W2 = (const float*)d_in[3];
  float* out = (float*)d_out;

  // Workspace (~144.7 MiB): Xb, Wb, Lp, C1p, C2p, cmax, pmax
  char* ws = (char*)d_ws;
  unsigned short* Xb = (unsigned short*)ws;
  unsigned short* Wb = (unsigned short*)(ws + 33554432);
  unsigned short* Lp = (unsigned short*)(ws + 33554432 + 6291456);
  unsigned short* C1p = (unsigned short*)(ws + 2 * 33554432 + 6291456);
  unsigned short* C2p = (unsigned short*)(ws + 3 * 33554432 + 6291456);
  float* cmax = (float*)(ws + 4 * 33554432 + 6291456);
  float* pmax = (float*)(ws + 4 * 33554432 + 6291456 + 2097152);

  convert_kernel<<<19456, 256, 0, stream>>>(X, W0, W1, W2, Xb, Wb);

  // 12 n-tiles x 64 m-tiles = 768 blocks (XCD-swizzled inside the kernel)
  gemm256_kernel<<<768, 512, 131072, stream>>>((const bf16_t*)Xb, (const bf16_t*)Wb,
                                               Lp, C1p, C2p, cmax);

  dim3 pgrid(4, BATCH);
  prefix_kernel<<<pgrid, 256, 0, stream>>>(cmax, pmax);

  dim3 fgrid(SEQ, BATCH);
  final_kernel<<<fgrid, 256, 0, stream>>>(Lp, C1p, C2p, pmax, out);
}